// Round 5
// baseline (547.872 us; speedup 1.0000x reference)
//
#include <hip/hip_runtime.h>
#include <cstdint>
#include <cstddef>

typedef __bf16 bf16x8 __attribute__((ext_vector_type(8)));
typedef __bf16 bf16x4 __attribute__((ext_vector_type(4)));
typedef short s16x4 __attribute__((ext_vector_type(4)));
typedef float f32x4 __attribute__((ext_vector_type(4)));

__device__ __forceinline__ ushort f2bf(float f) {
  union { float f; uint32_t u; } v; v.f = f;
  uint32_t r = (v.u + 0x7fffu + ((v.u >> 16) & 1u)) >> 16;
  return (ushort)r;
}

__device__ __forceinline__ float fast_exp2(float x) {
#if defined(__HIP_DEVICE_COMPILE__) && __has_builtin(__builtin_amdgcn_exp2f)
  return __builtin_amdgcn_exp2f(x);
#else
  return exp2f(x);
#endif
}

// K=16 bf16 MFMA (C-layout of a 16x16 result feeds directly as B operand).
// __has_builtin guards live inside __HIP_DEVICE_COMPILE__ (host pass has no amdgcn builtins).
__device__ __forceinline__ f32x4 mfma16(bf16x4 a, bf16x4 b, f32x4 c) {
#if defined(__HIP_DEVICE_COMPILE__)
#if __has_builtin(__builtin_amdgcn_mfma_f32_16x16x16_bf16)
  return __builtin_amdgcn_mfma_f32_16x16x16_bf16(a, b, c, 0, 0, 0);
#else
  return __builtin_amdgcn_mfma_f32_16x16x16bf16_1k(
      __builtin_bit_cast(s16x4, a), __builtin_bit_cast(s16x4, b), c, 0, 0, 0);
#endif
#else
  (void)a; (void)b;
  return c;  // host stub, never executed
#endif
}

// ---------------- fp32 -> bf16 convert (vectorized) ----------------
__global__ void conv_bf16(const float4* __restrict__ in, ushort4* __restrict__ out, int n4) {
  int i = blockIdx.x * blockDim.x + threadIdx.x;
  if (i < n4) {
    float4 v = in[i];
    ushort4 o;
    o.x = f2bf(v.x); o.y = f2bf(v.y); o.z = f2bf(v.z); o.w = f2bf(v.w);
    out[i] = o;
  }
}

// ---------------- fp32 [R][C] -> bf16 [C][R] transpose ----------------
__global__ void transpose_f32_bf16(const float* __restrict__ in, ushort* __restrict__ out,
                                   int R, int C) {
  __shared__ ushort t[32][33];
  int c0 = blockIdx.x * 32, r0 = blockIdx.y * 32;
  int tx = threadIdx.x, ty = threadIdx.y;  // 32 x 8
#pragma unroll
  for (int i = 0; i < 4; ++i)
    t[ty + i * 8][tx] = f2bf(in[(size_t)(r0 + ty + i * 8) * C + c0 + tx]);
  __syncthreads();
#pragma unroll
  for (int i = 0; i < 4; ++i)
    out[(size_t)(c0 + ty + i * 8) * R + r0 + tx] = t[tx][ty + i * 8];
}

// ---------------- bf16 GEMM: C = A[M][K] @ Bt[N][K]^T + bias ----------------
// MODE 0: scatter epilogue -> Q[B,H,S,64] (scaled 0.125*log2e), K[B,H,S,64],
//         V^T tiled: Vt[bh][s>>6][d][s&63]
// MODE 1: fp32 out[row*N+col]
template <int MODE>
__launch_bounds__(256)
__global__ void gemm_bt(const ushort* __restrict__ A, const ushort* __restrict__ Bt,
                        const float* __restrict__ bias,
                        ushort* __restrict__ o0, ushort* __restrict__ o1,
                        ushort* __restrict__ o2, float* __restrict__ of,
                        int M, int N, int K) {
  __shared__ ushort As[128 * 32];
  __shared__ ushort Bs[128 * 32];
  const int tid = threadIdx.x;
  const int wid = tid >> 6;
  const int lane = tid & 63;
  const int quad = lane >> 4;
  const int l16 = lane & 15;
  const int m0 = blockIdx.y * 128;
  const int n0 = blockIdx.x * 128;
  const int wm = (wid >> 1) * 64;
  const int wn = (wid & 1) * 64;
  const int srow = lane >> 2;          // 0..15
  const int scol = (lane & 3) << 3;    // 0,8,16,24

  f32x4 acc[4][4];
#pragma unroll
  for (int i = 0; i < 4; ++i)
#pragma unroll
    for (int j = 0; j < 4; ++j) acc[i][j] = (f32x4){0.f, 0.f, 0.f, 0.f};

  const int c0 = wid * 2, c1 = wid * 2 + 1;
  const ushort* gA0 = A + (size_t)(m0 + c0 * 16 + srow) * K + scol;
  const ushort* gA1 = A + (size_t)(m0 + c1 * 16 + srow) * K + scol;
  const ushort* gB0 = Bt + (size_t)(n0 + c0 * 16 + srow) * K + scol;
  const ushort* gB1 = Bt + (size_t)(n0 + c1 * 16 + srow) * K + scol;
  ushort* lA0 = As + c0 * 512 + lane * 8;
  ushort* lA1 = As + c1 * 512 + lane * 8;
  ushort* lB0 = Bs + c0 * 512 + lane * 8;
  ushort* lB1 = Bs + c1 * 512 + lane * 8;

  for (int k0 = 0; k0 < K; k0 += 32) {
    __syncthreads();
    __builtin_amdgcn_global_load_lds((const __attribute__((address_space(1))) void*)(gA0 + k0),
                                     (__attribute__((address_space(3))) void*)lA0, 16, 0, 0);
    __builtin_amdgcn_global_load_lds((const __attribute__((address_space(1))) void*)(gA1 + k0),
                                     (__attribute__((address_space(3))) void*)lA1, 16, 0, 0);
    __builtin_amdgcn_global_load_lds((const __attribute__((address_space(1))) void*)(gB0 + k0),
                                     (__attribute__((address_space(3))) void*)lB0, 16, 0, 0);
    __builtin_amdgcn_global_load_lds((const __attribute__((address_space(1))) void*)(gB1 + k0),
                                     (__attribute__((address_space(3))) void*)lB1, 16, 0, 0);
    __syncthreads();
    bf16x8 af[4], bfr[4];
#pragma unroll
    for (int i = 0; i < 4; ++i)
      af[i] = *(const bf16x8*)(As + (wm + i * 16 + l16) * 32 + quad * 8);
#pragma unroll
    for (int j = 0; j < 4; ++j)
      bfr[j] = *(const bf16x8*)(Bs + (wn + j * 16 + l16) * 32 + quad * 8);
#pragma unroll
    for (int i = 0; i < 4; ++i)
#pragma unroll
      for (int j = 0; j < 4; ++j)
        acc[i][j] = __builtin_amdgcn_mfma_f32_16x16x32_bf16(af[i], bfr[j], acc[i][j], 0, 0, 0);
  }

#pragma unroll
  for (int i = 0; i < 4; ++i) {
#pragma unroll
    for (int j = 0; j < 4; ++j) {
      const int col = n0 + wn + j * 16 + l16;
      const float bv = bias[col];
#pragma unroll
      for (int r = 0; r < 4; ++r) {
        const int row = m0 + wm + i * 16 + quad * 4 + r;
        float v = acc[i][j][r] + bv;
        if (MODE == 0) {
          const int sel = col >> 10, cr = col & 1023;
          const int h = cr >> 6, d = cr & 63;
          const int b = row >> 11, s = row & 2047;
          const size_t bh = (size_t)(b * 16 + h);
          if (sel == 0) v *= 0.18033688011112042f;  // (1/8) * log2(e): exp folded to exp2
          const ushort u = f2bf(v);
          if (sel == 0)       o0[(bh * 2048 + s) * 64 + d] = u;
          else if (sel == 1)  o1[(bh * 2048 + s) * 64 + d] = u;
          else                o2[((bh * 32 + (s >> 6)) << 12) + (d << 6) + (s & 63)] = u;
        } else {
          of[(size_t)row * N + col] = v;
        }
      }
    }
  }
}

// ---------------- flash attention (causal), block = (b,h) x 128 q-rows ----------------
// BARRIER-FREE, LDS-FREE: every MFMA operand is a contiguous 16B/8B per-lane slice of
// global memory (V pre-tiled as Vt[bh][kvtile][d][64] by gemm1). S' = K@Q^T (16x16x32),
// whose C-layout feeds PV (O^T = V^T @ P^T, 16x16x16) straight from registers.
// Each wave runs its own KV stream with its own trip count; latency hidden by TLP.
__launch_bounds__(256)
__global__ void attn_fused(const ushort* __restrict__ Qb, const ushort* __restrict__ Kb,
                           const ushort* __restrict__ Vt, ushort* __restrict__ Ob) {
  const int bh = blockIdx.y;                            // b*16 + h
  const int qt = (int)gridDim.x - 1 - (int)blockIdx.x;  // longest blocks dispatch first
  const int tid = threadIdx.x;
  const int wid = tid >> 6;
  const int lane = tid & 63;
  const int quad = lane >> 4;
  const int l16 = lane & 15;

  const int qg0 = qt * 128 + wid * 32;  // wave's min q-row

  // Q fragments direct from global (B-operand of 16x16x32: col=l16, k(d)=h*32+quad*8)
  const ushort* Qg = Qb + ((size_t)bh * 2048 + qg0) * 64;
  bf16x8 qa[2][2];
#pragma unroll
  for (int f = 0; f < 2; ++f)
#pragma unroll
    for (int h = 0; h < 2; ++h)
      qa[f][h] = *(const bf16x8*)(Qg + (f * 16 + l16) * 64 + h * 32 + quad * 8);

  f32x4 o[2][4];  // O^T accum: [qfrag][dfrag], row=d(quad*4+r), col=q(l16)
  float rs[2];    // per-lane row sum for col q = l16
#pragma unroll
  for (int f = 0; f < 2; ++f) {
    rs[f] = 0.f;
#pragma unroll
    for (int m = 0; m < 4; ++m) o[f][m] = (f32x4){0.f, 0.f, 0.f, 0.f};
  }

  const ushort* Kg = Kb + (size_t)bh * 2048 * 64;       // [s][64]
  const ushort* Vg = Vt + ((size_t)bh * 32) * 4096;     // [tile][d][64]

  const int nIt = ((qg0 + 31) >> 6) + 1;  // per-wave trip count (tail tiles skipped)
  for (int jt = 0; jt < nIt; ++jt) {
    const int kvb = jt * 64;

    // K fragments: A-operand rows kv=n*16+l16, k(d)=h*32+quad*8 — 16B contiguous
    bf16x8 kb[4][2];
#pragma unroll
    for (int n = 0; n < 4; ++n)
#pragma unroll
      for (int h = 0; h < 2; ++h)
        kb[n][h] = *(const bf16x8*)(Kg + (size_t)(kvb + n * 16 + l16) * 64 + h * 32 + quad * 8);

    // S' = K @ Q^T : rows kv, cols q
    f32x4 s[2][4];
#pragma unroll
    for (int n = 0; n < 4; ++n)
#pragma unroll
      for (int f = 0; f < 2; ++f) {
        f32x4 z = (f32x4){0.f, 0.f, 0.f, 0.f};
        z = __builtin_amdgcn_mfma_f32_16x16x32_bf16(kb[n][0], qa[f][0], z, 0, 0, 0);
        z = __builtin_amdgcn_mfma_f32_16x16x32_bf16(kb[n][1], qa[f][1], z, 0, 0, 0);
        s[f][n] = z;
      }

    // V fragments (issued while exp runs): A-operand rows d=m*16+l16, k(kv)=n*16+quad*4
    bf16x4 va[4][4];
    const ushort* Vtile = Vg + (size_t)jt * 4096;
#pragma unroll
    for (int m = 0; m < 4; ++m)
#pragma unroll
      for (int n = 0; n < 4; ++n)
        va[m][n] = *(const bf16x4*)(Vtile + (m * 16 + l16) * 64 + n * 16 + quad * 4);

    // exp2 + per-lane row-sum + pack P as 16x16x16 B-operand (all in-lane)
    bf16x4 p[2][4];
    if (kvb + 63 <= qg0) {  // whole tile unmasked for this wave
#pragma unroll
      for (int f = 0; f < 2; ++f)
#pragma unroll
        for (int n = 0; n < 4; ++n) {
          float pe[4];
#pragma unroll
          for (int r = 0; r < 4; ++r) {
            pe[r] = fast_exp2(s[f][n][r]);
            rs[f] += pe[r];
          }
          p[f][n] = (bf16x4){(__bf16)pe[0], (__bf16)pe[1], (__bf16)pe[2], (__bf16)pe[3]};
        }
    } else {
#pragma unroll
      for (int f = 0; f < 2; ++f) {
        const int qg = qg0 + f * 16 + l16;
#pragma unroll
        for (int n = 0; n < 4; ++n) {
          const int kg0 = kvb + n * 16 + quad * 4;
          float pe[4];
#pragma unroll
          for (int r = 0; r < 4; ++r) {
            float e = fast_exp2(s[f][n][r]);
            pe[r] = (kg0 + r > qg) ? 0.f : e;
            rs[f] += pe[r];
          }
          p[f][n] = (bf16x4){(__bf16)pe[0], (__bf16)pe[1], (__bf16)pe[2], (__bf16)pe[3]};
        }
      }
    }

    // O^T += V^T @ P^T
#pragma unroll
    for (int m = 0; m < 4; ++m)
#pragma unroll
      for (int n = 0; n < 4; ++n)
#pragma unroll
        for (int f = 0; f < 2; ++f) o[f][m] = mfma16(va[m][n], p[f][n], o[f][m]);
  }

  // epilogue: reduce row sums across quads, normalize, store O (lane holds q=l16)
  const int b = bh >> 4, h = bh & 15;
#pragma unroll
  for (int f = 0; f < 2; ++f) {
    float t = rs[f];
    t += __shfl_xor(t, 16, 64);
    t += __shfl_xor(t, 32, 64);
    const float il = 1.f / t;
    const int q = qg0 + f * 16 + l16;
    ushort* dst = Ob + ((size_t)b * 2048 + q) * 1024 + h * 64;
#pragma unroll
    for (int m = 0; m < 4; ++m) {
      ushort4 w;
      w.x = f2bf(o[f][m][0] * il);
      w.y = f2bf(o[f][m][1] * il);
      w.z = f2bf(o[f][m][2] * il);
      w.w = f2bf(o[f][m][3] * il);
      *(ushort4*)(dst + m * 16 + quad * 4) = w;
    }
  }
}

// ---------------- launch ----------------
extern "C" void kernel_launch(void* const* d_in, const int* in_sizes, int n_in,
                              void* d_out, int out_size, void* d_ws, size_t ws_size,
                              hipStream_t stream) {
  const float* x    = (const float*)d_in[0];  // [4,2048,1024]
  const float* Wqkv = (const float*)d_in[1];  // [1024,3072]
  const float* bqkv = (const float*)d_in[2];  // [3072]
  const float* Wo   = (const float*)d_in[3];  // [1024,1024]
  const float* bo   = (const float*)d_in[4];  // [1024]
  float* out = (float*)d_out;                 // [4,2048,1024] fp32

  char* ws = (char*)d_ws;
  size_t off = 0;
  auto alloc = [&](size_t bytes) {
    void* p = ws + off;
    off += (bytes + 255) & ~(size_t)255;
    return p;
  };
  ushort* xbf    = (ushort*)alloc((size_t)8192 * 1024 * 2);
  ushort* Wqkv_t = (ushort*)alloc((size_t)3072 * 1024 * 2);
  ushort* Wo_t   = (ushort*)alloc((size_t)1024 * 1024 * 2);
  ushort* Qb     = (ushort*)alloc((size_t)64 * 2048 * 64 * 2);
  ushort* Kb     = (ushort*)alloc((size_t)64 * 2048 * 64 * 2);
  ushort* Vb     = (ushort*)alloc((size_t)64 * 2048 * 64 * 2);  // tiled V^T
  ushort* Ab     = (ushort*)alloc((size_t)8192 * 1024 * 2);

  // 1. x -> bf16
  conv_bf16<<<dim3(8192), dim3(256), 0, stream>>>((const float4*)x, (ushort4*)xbf,
                                                  8192 * 1024 / 4);
  // 2. transpose weights -> bf16 [N][K]
  transpose_f32_bf16<<<dim3(96, 32), dim3(32, 8), 0, stream>>>(Wqkv, Wqkv_t, 1024, 3072);
  transpose_f32_bf16<<<dim3(32, 32), dim3(32, 8), 0, stream>>>(Wo, Wo_t, 1024, 1024);
  // 3. QKV projection, scatter to Q/K/Vt layouts (Q pre-scaled by 0.125*log2e)
  gemm_bt<0><<<dim3(24, 64), dim3(256), 0, stream>>>(xbf, Wqkv_t, bqkv, Qb, Kb, Vb, nullptr,
                                                     8192, 3072, 1024);
  // 4. causal flash attention (128 q-rows per block, barrier-free)
  attn_fused<<<dim3(16, 64), dim3(256), 0, stream>>>(Qb, Kb, Vb, Ab);
  // 5. output projection
  gemm_bt<1><<<dim3(8, 64), dim3(256), 0, stream>>>(Ab, Wo_t, bo, nullptr, nullptr, nullptr,
                                                    out, 8192, 1024, 1024);
}

// Round 6
// 376.166 us; speedup vs baseline: 1.4565x; 1.4565x over previous
//
#include <hip/hip_runtime.h>
#include <cstdint>
#include <cstddef>

typedef __bf16 bf16x8 __attribute__((ext_vector_type(8)));
typedef __bf16 bf16x4 __attribute__((ext_vector_type(4)));
typedef short s16x4 __attribute__((ext_vector_type(4)));
typedef float f32x4 __attribute__((ext_vector_type(4)));

__device__ __forceinline__ ushort f2bf(float f) {
  union { float f; uint32_t u; } v; v.f = f;
  uint32_t r = (v.u + 0x7fffu + ((v.u >> 16) & 1u)) >> 16;
  return (ushort)r;
}

__device__ __forceinline__ float fast_exp2(float x) {
#if defined(__HIP_DEVICE_COMPILE__) && __has_builtin(__builtin_amdgcn_exp2f)
  return __builtin_amdgcn_exp2f(x);
#else
  return exp2f(x);
#endif
}

// K=16 bf16 MFMA (C-layout of a 16x16 result feeds directly as B operand).
// __has_builtin guards live inside __HIP_DEVICE_COMPILE__ (host pass has no amdgcn builtins).
__device__ __forceinline__ f32x4 mfma16(bf16x4 a, bf16x4 b, f32x4 c) {
#if defined(__HIP_DEVICE_COMPILE__)
#if __has_builtin(__builtin_amdgcn_mfma_f32_16x16x16_bf16)
  return __builtin_amdgcn_mfma_f32_16x16x16_bf16(a, b, c, 0, 0, 0);
#else
  return __builtin_amdgcn_mfma_f32_16x16x16bf16_1k(
      __builtin_bit_cast(s16x4, a), __builtin_bit_cast(s16x4, b), c, 0, 0, 0);
#endif
#else
  (void)a; (void)b;
  return c;  // host stub, never executed
#endif
}

__device__ __forceinline__ void glds16(const ushort* g, ushort* l) {
  __builtin_amdgcn_global_load_lds((const __attribute__((address_space(1))) void*)g,
                                   (__attribute__((address_space(3))) void*)l, 16, 0, 0);
}

// ---------------- fp32 -> bf16 convert (vectorized) ----------------
__global__ void conv_bf16(const float4* __restrict__ in, ushort4* __restrict__ out, int n4) {
  int i = blockIdx.x * blockDim.x + threadIdx.x;
  if (i < n4) {
    float4 v = in[i];
    ushort4 o;
    o.x = f2bf(v.x); o.y = f2bf(v.y); o.z = f2bf(v.z); o.w = f2bf(v.w);
    out[i] = o;
  }
}

// ---------------- fp32 [R][C] -> bf16 [C][R] transpose ----------------
__global__ void transpose_f32_bf16(const float* __restrict__ in, ushort* __restrict__ out,
                                   int R, int C) {
  __shared__ ushort t[32][33];
  int c0 = blockIdx.x * 32, r0 = blockIdx.y * 32;
  int tx = threadIdx.x, ty = threadIdx.y;  // 32 x 8
#pragma unroll
  for (int i = 0; i < 4; ++i)
    t[ty + i * 8][tx] = f2bf(in[(size_t)(r0 + ty + i * 8) * C + c0 + tx]);
  __syncthreads();
#pragma unroll
  for (int i = 0; i < 4; ++i)
    out[(size_t)(c0 + ty + i * 8) * R + r0 + tx] = t[tx][ty + i * 8];
}

// ---------------- bf16 GEMM: C = A[M][K] @ Bt[N][K]^T + bias ----------------
// MODE 0: scatter epilogue -> Q[B,H,S,64] (scaled 0.125*log2e), K[B,H,S,64],
//         V^T tiled: Vt[bh][s>>6][d][s&63]
// MODE 1: fp32 out[row*N+col]
template <int MODE>
__launch_bounds__(256)
__global__ void gemm_bt(const ushort* __restrict__ A, const ushort* __restrict__ Bt,
                        const float* __restrict__ bias,
                        ushort* __restrict__ o0, ushort* __restrict__ o1,
                        ushort* __restrict__ o2, float* __restrict__ of,
                        int M, int N, int K) {
  __shared__ ushort As[128 * 32];
  __shared__ ushort Bs[128 * 32];
  const int tid = threadIdx.x;
  const int wid = tid >> 6;
  const int lane = tid & 63;
  const int quad = lane >> 4;
  const int l16 = lane & 15;
  const int m0 = blockIdx.y * 128;
  const int n0 = blockIdx.x * 128;
  const int wm = (wid >> 1) * 64;
  const int wn = (wid & 1) * 64;
  const int srow = lane >> 2;          // 0..15
  const int scol = (lane & 3) << 3;    // 0,8,16,24

  f32x4 acc[4][4];
#pragma unroll
  for (int i = 0; i < 4; ++i)
#pragma unroll
    for (int j = 0; j < 4; ++j) acc[i][j] = (f32x4){0.f, 0.f, 0.f, 0.f};

  const int c0 = wid * 2, c1 = wid * 2 + 1;
  const ushort* gA0 = A + (size_t)(m0 + c0 * 16 + srow) * K + scol;
  const ushort* gA1 = A + (size_t)(m0 + c1 * 16 + srow) * K + scol;
  const ushort* gB0 = Bt + (size_t)(n0 + c0 * 16 + srow) * K + scol;
  const ushort* gB1 = Bt + (size_t)(n0 + c1 * 16 + srow) * K + scol;
  ushort* lA0 = As + c0 * 512 + lane * 8;
  ushort* lA1 = As + c1 * 512 + lane * 8;
  ushort* lB0 = Bs + c0 * 512 + lane * 8;
  ushort* lB1 = Bs + c1 * 512 + lane * 8;

  for (int k0 = 0; k0 < K; k0 += 32) {
    __syncthreads();
    glds16(gA0 + k0, lA0);
    glds16(gA1 + k0, lA1);
    glds16(gB0 + k0, lB0);
    glds16(gB1 + k0, lB1);
    __syncthreads();
    bf16x8 af[4], bfr[4];
#pragma unroll
    for (int i = 0; i < 4; ++i)
      af[i] = *(const bf16x8*)(As + (wm + i * 16 + l16) * 32 + quad * 8);
#pragma unroll
    for (int j = 0; j < 4; ++j)
      bfr[j] = *(const bf16x8*)(Bs + (wn + j * 16 + l16) * 32 + quad * 8);
#pragma unroll
    for (int i = 0; i < 4; ++i)
#pragma unroll
      for (int j = 0; j < 4; ++j)
        acc[i][j] = __builtin_amdgcn_mfma_f32_16x16x32_bf16(af[i], bfr[j], acc[i][j], 0, 0, 0);
  }

#pragma unroll
  for (int i = 0; i < 4; ++i) {
#pragma unroll
    for (int j = 0; j < 4; ++j) {
      const int col = n0 + wn + j * 16 + l16;
      const float bv = bias[col];
#pragma unroll
      for (int r = 0; r < 4; ++r) {
        const int row = m0 + wm + i * 16 + quad * 4 + r;
        float v = acc[i][j][r] + bv;
        if (MODE == 0) {
          const int sel = col >> 10, cr = col & 1023;
          const int h = cr >> 6, d = cr & 63;
          const int b = row >> 11, s = row & 2047;
          const size_t bh = (size_t)(b * 16 + h);
          if (sel == 0) v *= 0.18033688011112042f;  // (1/8) * log2(e): exp folded to exp2
          const ushort u = f2bf(v);
          if (sel == 0)       o0[(bh * 2048 + s) * 64 + d] = u;
          else if (sel == 1)  o1[(bh * 2048 + s) * 64 + d] = u;
          else                o2[((bh * 32 + (s >> 6)) << 12) + (d << 6) + (s & 63)] = u;
        } else {
          of[(size_t)row * N + col] = v;
        }
      }
    }
  }
}

// ---------------- flash attention (causal), block = (b,h) x 128 q-rows ----------------
// Single-barrier, double-buffered DMA staging: global_load_lds(16B) ping-pong K/V tiles.
// The compiler's auto vmcnt(0)-before-barrier drains loads issued a full compute phase
// earlier (cheap). K/V tiles stored as lo/hi [64][32] half-tiles (64B row stride — the
// proven m97 bank pattern; global_load_lds forbids padding). P stays in registers:
// S' = K@Q^T (16x16x32) C-layout feeds PV O^T = V^T@P^T (16x16x16) directly.
__launch_bounds__(256)
__global__ void attn_fused(const ushort* __restrict__ Qb, const ushort* __restrict__ Kb,
                           const ushort* __restrict__ Vt, ushort* __restrict__ Ob) {
  const int bh = blockIdx.y;                            // b*16 + h
  const int qt = (int)gridDim.x - 1 - (int)blockIdx.x;  // longest blocks dispatch first
  const int tid = threadIdx.x;
  const int wid = tid >> 6;
  const int lane = tid & 63;
  const int quad = lane >> 4;
  const int l16 = lane & 15;

  __shared__ ushort Ks[2][2][64 * 32];  // [buf][half(d)][row=kv][32 d-elems]
  __shared__ ushort Vs[2][2][64 * 32];  // [buf][half(kv)][row=d][32 kv-elems]

  const int qg0 = qt * 128 + wid * 32;  // wave's min q-row

  // Q fragments direct from global (B-operand of 16x16x32: col=l16, k(d)=h*32+quad*8)
  const ushort* Qg = Qb + ((size_t)bh * 2048 + qg0) * 64;
  bf16x8 qa[2][2];
#pragma unroll
  for (int f = 0; f < 2; ++f)
#pragma unroll
    for (int h = 0; h < 2; ++h)
      qa[f][h] = *(const bf16x8*)(Qg + (f * 16 + l16) * 64 + h * 32 + quad * 8);

  // staging: wave w covers rows w*16..w*16+15 of each half-tile; lane = lr*4 + c
  const int lr = lane >> 2, c = (lane & 3) << 3;  // c in elems (0,8,16,24)
  const ushort* Kg = Kb + (size_t)bh * 2048 * 64 + (size_t)(wid * 16 + lr) * 64 + c;
  const ushort* Vg = Vt + (size_t)bh * 32 * 4096 + (size_t)(wid * 16 + lr) * 64 + c;
  ushort* ldsK0[2], *ldsK1[2], *ldsV0[2], *ldsV1[2];
#pragma unroll
  for (int buf = 0; buf < 2; ++buf) {
    ldsK0[buf] = &Ks[buf][0][wid * 16 * 32] + lane * 8;
    ldsK1[buf] = &Ks[buf][1][wid * 16 * 32] + lane * 8;
    ldsV0[buf] = &Vs[buf][0][wid * 16 * 32] + lane * 8;
    ldsV1[buf] = &Vs[buf][1][wid * 16 * 32] + lane * 8;
  }
  auto stage = [&](int jt) {
    const int buf = jt & 1;
    const ushort* ks = Kg + (size_t)jt * 4096;
    const ushort* vs = Vg + (size_t)jt * 4096;
    glds16(ks, ldsK0[buf]);
    glds16(ks + 32, ldsK1[buf]);
    glds16(vs, ldsV0[buf]);
    glds16(vs + 32, ldsV1[buf]);
  };

  f32x4 o[2][4];  // O^T accum: [qfrag][dfrag], row=d(quad*4+r), col=q(l16)
  float rs[2];
#pragma unroll
  for (int f = 0; f < 2; ++f) {
    rs[f] = 0.f;
#pragma unroll
    for (int m = 0; m < 4; ++m) o[f][m] = (f32x4){0.f, 0.f, 0.f, 0.f};
  }

  const int nIt = 2 * qt + 2;  // block-uniform trip count
  stage(0);

  for (int jt = 0; jt < nIt; ++jt) {
    __syncthreads();                   // auto vmcnt(0): tile jt landed; buf (jt+1)&1 free
    if (jt + 1 < nIt) stage(jt + 1);   // DMA next tile; lands during this compute phase

    const int kvb = jt * 64;
    if (kvb > qg0 + 31) continue;      // fully-masked for this wave (no barriers below)
    const int buf = jt & 1;

    // K fragments: A-operand rows kv=n*16+l16, k(d)=h*32+quad*8
    f32x4 s[2][4];
#pragma unroll
    for (int n = 0; n < 4; ++n) {
      bf16x8 kb0 = *(const bf16x8*)&Ks[buf][0][(n * 16 + l16) * 32 + quad * 8];
      bf16x8 kb1 = *(const bf16x8*)&Ks[buf][1][(n * 16 + l16) * 32 + quad * 8];
#pragma unroll
      for (int f = 0; f < 2; ++f) {
        f32x4 z = (f32x4){0.f, 0.f, 0.f, 0.f};
        z = __builtin_amdgcn_mfma_f32_16x16x32_bf16(kb0, qa[f][0], z, 0, 0, 0);
        z = __builtin_amdgcn_mfma_f32_16x16x32_bf16(kb1, qa[f][1], z, 0, 0, 0);
        s[f][n] = z;
      }
    }

    // exp2 + per-lane row-sum + pack P as 16x16x16 B-operand (all in-lane)
    bf16x4 p[2][4];
    if (kvb + 63 <= qg0) {
#pragma unroll
      for (int f = 0; f < 2; ++f)
#pragma unroll
        for (int n = 0; n < 4; ++n) {
          float pe[4];
#pragma unroll
          for (int r = 0; r < 4; ++r) {
            pe[r] = fast_exp2(s[f][n][r]);
            rs[f] += pe[r];
          }
          p[f][n] = (bf16x4){(__bf16)pe[0], (__bf16)pe[1], (__bf16)pe[2], (__bf16)pe[3]};
        }
    } else {
#pragma unroll
      for (int f = 0; f < 2; ++f) {
        const int qg = qg0 + f * 16 + l16;
#pragma unroll
        for (int n = 0; n < 4; ++n) {
          const int kg0 = kvb + n * 16 + quad * 4;
          float pe[4];
#pragma unroll
          for (int r = 0; r < 4; ++r) {
            float e = fast_exp2(s[f][n][r]);
            pe[r] = (kg0 + r > qg) ? 0.f : e;
            rs[f] += pe[r];
          }
          p[f][n] = (bf16x4){(__bf16)pe[0], (__bf16)pe[1], (__bf16)pe[2], (__bf16)pe[3]};
        }
      }
    }

    // O^T += V^T @ P^T  (A-operand: Vs rows d=m*16+l16, k(kv)=n*16+quad*4)
#pragma unroll
    for (int m = 0; m < 4; ++m)
#pragma unroll
      for (int n = 0; n < 4; ++n) {
        bf16x4 va = *(const bf16x4*)&Vs[buf][n >> 1][(m * 16 + l16) * 32 + (n & 1) * 16 + quad * 4];
#pragma unroll
        for (int f = 0; f < 2; ++f) o[f][m] = mfma16(va, p[f][n], o[f][m]);
      }
  }

  // epilogue: reduce row sums across quads, normalize, store O (lane holds q=l16)
  const int b = bh >> 4, h = bh & 15;
#pragma unroll
  for (int f = 0; f < 2; ++f) {
    float t = rs[f];
    t += __shfl_xor(t, 16, 64);
    t += __shfl_xor(t, 32, 64);
    const float il = 1.f / t;
    const int q = qg0 + f * 16 + l16;
    ushort* dst = Ob + ((size_t)b * 2048 + q) * 1024 + h * 64;
#pragma unroll
    for (int m = 0; m < 4; ++m) {
      ushort4 w;
      w.x = f2bf(o[f][m][0] * il);
      w.y = f2bf(o[f][m][1] * il);
      w.z = f2bf(o[f][m][2] * il);
      w.w = f2bf(o[f][m][3] * il);
      *(ushort4*)(dst + m * 16 + quad * 4) = w;
    }
  }
}

// ---------------- launch ----------------
extern "C" void kernel_launch(void* const* d_in, const int* in_sizes, int n_in,
                              void* d_out, int out_size, void* d_ws, size_t ws_size,
                              hipStream_t stream) {
  const float* x    = (const float*)d_in[0];  // [4,2048,1024]
  const float* Wqkv = (const float*)d_in[1];  // [1024,3072]
  const float* bqkv = (const float*)d_in[2];  // [3072]
  const float* Wo   = (const float*)d_in[3];  // [1024,1024]
  const float* bo   = (const float*)d_in[4];  // [1024]
  float* out = (float*)d_out;                 // [4,2048,1024] fp32

  char* ws = (char*)d_ws;
  size_t off = 0;
  auto alloc = [&](size_t bytes) {
    void* p = ws + off;
    off += (bytes + 255) & ~(size_t)255;
    return p;
  };
  ushort* xbf    = (ushort*)alloc((size_t)8192 * 1024 * 2);
  ushort* Wqkv_t = (ushort*)alloc((size_t)3072 * 1024 * 2);
  ushort* Wo_t   = (ushort*)alloc((size_t)1024 * 1024 * 2);
  ushort* Qb     = (ushort*)alloc((size_t)64 * 2048 * 64 * 2);
  ushort* Kb     = (ushort*)alloc((size_t)64 * 2048 * 64 * 2);
  ushort* Vb     = (ushort*)alloc((size_t)64 * 2048 * 64 * 2);  // tiled V^T
  ushort* Ab     = (ushort*)alloc((size_t)8192 * 1024 * 2);

  // 1. x -> bf16
  conv_bf16<<<dim3(8192), dim3(256), 0, stream>>>((const float4*)x, (ushort4*)xbf,
                                                  8192 * 1024 / 4);
  // 2. transpose weights -> bf16 [N][K]
  transpose_f32_bf16<<<dim3(96, 32), dim3(32, 8), 0, stream>>>(Wqkv, Wqkv_t, 1024, 3072);
  transpose_f32_bf16<<<dim3(32, 32), dim3(32, 8), 0, stream>>>(Wo, Wo_t, 1024, 1024);
  // 3. QKV projection, scatter to Q/K/Vt layouts (Q pre-scaled by 0.125*log2e)
  gemm_bt<0><<<dim3(24, 64), dim3(256), 0, stream>>>(xbf, Wqkv_t, bqkv, Qb, Kb, Vb, nullptr,
                                                     8192, 3072, 1024);
  // 4. causal flash attention (128 q-rows per block, single-barrier dbuf staging)
  attn_fused<<<dim3(16, 64), dim3(256), 0, stream>>>(Qb, Kb, Vb, Ab);
  // 5. output projection
  gemm_bt<1><<<dim3(8, 64), dim3(256), 0, stream>>>(Ab, Wo_t, bo, nullptr, nullptr, nullptr,
                                                    out, 8192, 1024, 1024);
}

// Round 7
// 281.114 us; speedup vs baseline: 1.9489x; 1.3381x over previous
//
#include <hip/hip_runtime.h>
#include <cstdint>
#include <cstddef>

typedef __bf16 bf16x8 __attribute__((ext_vector_type(8)));
typedef __bf16 bf16x4 __attribute__((ext_vector_type(4)));
typedef short s16x4 __attribute__((ext_vector_type(4)));
typedef float f32x4 __attribute__((ext_vector_type(4)));

__device__ __forceinline__ ushort f2bf(float f) {
  union { float f; uint32_t u; } v; v.f = f;
  uint32_t r = (v.u + 0x7fffu + ((v.u >> 16) & 1u)) >> 16;
  return (ushort)r;
}

__device__ __forceinline__ float fast_exp2(float x) {
#if defined(__HIP_DEVICE_COMPILE__) && __has_builtin(__builtin_amdgcn_exp2f)
  return __builtin_amdgcn_exp2f(x);
#else
  return exp2f(x);
#endif
}

// K=16 bf16 MFMA (C-layout of a 16x16 result feeds directly as B operand).
// __has_builtin guards live inside __HIP_DEVICE_COMPILE__ (host pass has no amdgcn builtins).
__device__ __forceinline__ f32x4 mfma16(bf16x4 a, bf16x4 b, f32x4 c) {
#if defined(__HIP_DEVICE_COMPILE__)
#if __has_builtin(__builtin_amdgcn_mfma_f32_16x16x16_bf16)
  return __builtin_amdgcn_mfma_f32_16x16x16_bf16(a, b, c, 0, 0, 0);
#else
  return __builtin_amdgcn_mfma_f32_16x16x16bf16_1k(
      __builtin_bit_cast(s16x4, a), __builtin_bit_cast(s16x4, b), c, 0, 0, 0);
#endif
#else
  (void)a; (void)b;
  return c;  // host stub, never executed
#endif
}

__device__ __forceinline__ void glds16(const ushort* g, ushort* l) {
  __builtin_amdgcn_global_load_lds((const __attribute__((address_space(1))) void*)g,
                                   (__attribute__((address_space(3))) void*)l, 16, 0, 0);
}

// ---------------- fp32 -> bf16 convert (vectorized) ----------------
__global__ void conv_bf16(const float4* __restrict__ in, ushort4* __restrict__ out, int n4) {
  int i = blockIdx.x * blockDim.x + threadIdx.x;
  if (i < n4) {
    float4 v = in[i];
    ushort4 o;
    o.x = f2bf(v.x); o.y = f2bf(v.y); o.z = f2bf(v.z); o.w = f2bf(v.w);
    out[i] = o;
  }
}

// ---------------- fp32 [R][C] -> bf16 [C][R] transpose ----------------
__global__ void transpose_f32_bf16(const float* __restrict__ in, ushort* __restrict__ out,
                                   int R, int C) {
  __shared__ ushort t[32][33];
  int c0 = blockIdx.x * 32, r0 = blockIdx.y * 32;
  int tx = threadIdx.x, ty = threadIdx.y;  // 32 x 8
#pragma unroll
  for (int i = 0; i < 4; ++i)
    t[ty + i * 8][tx] = f2bf(in[(size_t)(r0 + ty + i * 8) * C + c0 + tx]);
  __syncthreads();
#pragma unroll
  for (int i = 0; i < 4; ++i)
    out[(size_t)(c0 + ty + i * 8) * R + r0 + tx] = t[tx][ty + i * 8];
}

// ---------------- bf16 GEMM: C = A[M][K] @ Bt[N][K]^T + bias ----------------
// MODE 0: scatter epilogue -> Q[B,H,S,64] (scaled 0.125*log2e), K[B,H,S,64],
//         V^T tiled: Vt[bh][s>>6][d][s&63]
// MODE 1: fp32 out[row*N+col]
template <int MODE>
__launch_bounds__(256)
__global__ void gemm_bt(const ushort* __restrict__ A, const ushort* __restrict__ Bt,
                        const float* __restrict__ bias,
                        ushort* __restrict__ o0, ushort* __restrict__ o1,
                        ushort* __restrict__ o2, float* __restrict__ of,
                        int M, int N, int K) {
  __shared__ ushort As[128 * 32];
  __shared__ ushort Bs[128 * 32];
  const int tid = threadIdx.x;
  const int wid = tid >> 6;
  const int lane = tid & 63;
  const int quad = lane >> 4;
  const int l16 = lane & 15;
  const int m0 = blockIdx.y * 128;
  const int n0 = blockIdx.x * 128;
  const int wm = (wid >> 1) * 64;
  const int wn = (wid & 1) * 64;
  const int srow = lane >> 2;          // 0..15
  const int scol = (lane & 3) << 3;    // 0,8,16,24

  f32x4 acc[4][4];
#pragma unroll
  for (int i = 0; i < 4; ++i)
#pragma unroll
    for (int j = 0; j < 4; ++j) acc[i][j] = (f32x4){0.f, 0.f, 0.f, 0.f};

  const int c0 = wid * 2, c1 = wid * 2 + 1;
  const ushort* gA0 = A + (size_t)(m0 + c0 * 16 + srow) * K + scol;
  const ushort* gA1 = A + (size_t)(m0 + c1 * 16 + srow) * K + scol;
  const ushort* gB0 = Bt + (size_t)(n0 + c0 * 16 + srow) * K + scol;
  const ushort* gB1 = Bt + (size_t)(n0 + c1 * 16 + srow) * K + scol;
  ushort* lA0 = As + c0 * 512 + lane * 8;
  ushort* lA1 = As + c1 * 512 + lane * 8;
  ushort* lB0 = Bs + c0 * 512 + lane * 8;
  ushort* lB1 = Bs + c1 * 512 + lane * 8;

  for (int k0 = 0; k0 < K; k0 += 32) {
    __syncthreads();
    glds16(gA0 + k0, lA0);
    glds16(gA1 + k0, lA1);
    glds16(gB0 + k0, lB0);
    glds16(gB1 + k0, lB1);
    __syncthreads();
    bf16x8 af[4], bfr[4];
#pragma unroll
    for (int i = 0; i < 4; ++i)
      af[i] = *(const bf16x8*)(As + (wm + i * 16 + l16) * 32 + quad * 8);
#pragma unroll
    for (int j = 0; j < 4; ++j)
      bfr[j] = *(const bf16x8*)(Bs + (wn + j * 16 + l16) * 32 + quad * 8);
#pragma unroll
    for (int i = 0; i < 4; ++i)
#pragma unroll
      for (int j = 0; j < 4; ++j)
        acc[i][j] = __builtin_amdgcn_mfma_f32_16x16x32_bf16(af[i], bfr[j], acc[i][j], 0, 0, 0);
  }

#pragma unroll
  for (int i = 0; i < 4; ++i) {
#pragma unroll
    for (int j = 0; j < 4; ++j) {
      const int col = n0 + wn + j * 16 + l16;
      const float bv = bias[col];
#pragma unroll
      for (int r = 0; r < 4; ++r) {
        const int row = m0 + wm + i * 16 + quad * 4 + r;
        float v = acc[i][j][r] + bv;
        if (MODE == 0) {
          const int sel = col >> 10, cr = col & 1023;
          const int h = cr >> 6, d = cr & 63;
          const int b = row >> 11, s = row & 2047;
          const size_t bh = (size_t)(b * 16 + h);
          if (sel == 0) v *= 0.18033688011112042f;  // (1/8) * log2(e): exp folded to exp2
          const ushort u = f2bf(v);
          if (sel == 0)       o0[(bh * 2048 + s) * 64 + d] = u;
          else if (sel == 1)  o1[(bh * 2048 + s) * 64 + d] = u;
          else                o2[((bh * 32 + (s >> 6)) << 12) + (d << 6) + (s & 63)] = u;
        } else {
          of[(size_t)row * N + col] = v;
        }
      }
    }
  }
}

// ---------------- flash attention (causal) ----------------
// Block p of 8 processes q-tiles {p, 15-p} (128 rows each) for its (b,h):
// (2p+2)+(2(15-p)+2) = 34 KV-iters for EVERY block -> perfectly uniform grid of
// 512 blocks = 2/CU, no tail (R6's 11% occupancy was tail-dominated).
// Single-barrier dbuf global_load_lds staging. LDS layout is XOR-swizzled at the
// SOURCE (DMA dest is forced to base+lane*16B): physical chunk j holds logical
// chunk j^((row>>1)&3) -> b128/b64 reads land 2-way-aliased (free) instead of 8-way.
// P stays in registers: S'=K@Q^T (16x16x32) C-layout feeds PV (16x16x16) directly.
__launch_bounds__(256)
__global__ void attn_fused(const ushort* __restrict__ Qb, const ushort* __restrict__ Kb,
                           const ushort* __restrict__ Vt, ushort* __restrict__ Ob) {
  const int bh = blockIdx.y;       // b*16 + h
  const int pair = blockIdx.x;     // 0..7
  const int tid = threadIdx.x;
  const int wid = tid >> 6;
  const int lane = tid & 63;
  const int quad = lane >> 4;
  const int l16 = lane & 15;

  __shared__ ushort Ks[2][2][64 * 32];  // [buf][half(d)][row=kv][32 d-elems] (swizzled)
  __shared__ ushort Vs[2][2][64 * 32];  // [buf][half(kv)][row=d][32 kv-elems] (swizzled)

  // staging: wave w covers rows w*16..w*16+15; lane -> (row = w*16 + lane>>2, j_phys = lane&3)
  const int lr = lane >> 2;
  const int jphys = lane & 3;
  const int skey = (lr >> 1) & 3;           // swizzle key for this lane's staged row
  const int jlog = jphys ^ skey;            // logical chunk this lane fetches
  const int srow = wid * 16 + lr;           // row within 64-row tile
  const ushort* KgL = Kb + (size_t)bh * 2048 * 64 + (size_t)srow * 64 + jlog * 8;
  const ushort* VgL = Vt + (size_t)bh * 32 * 4096 + (size_t)srow * 64 + jlog * 8;
  ushort* ldsK0[2], *ldsK1[2], *ldsV0[2], *ldsV1[2];
#pragma unroll
  for (int buf = 0; buf < 2; ++buf) {
    ldsK0[buf] = &Ks[buf][0][wid * 16 * 32] + lane * 8;
    ldsK1[buf] = &Ks[buf][1][wid * 16 * 32] + lane * 8;
    ldsV0[buf] = &Vs[buf][0][wid * 16 * 32] + lane * 8;
    ldsV1[buf] = &Vs[buf][1][wid * 16 * 32] + lane * 8;
  }
  auto stage = [&](int jt) {
    const int buf = jt & 1;
    const ushort* ks = KgL + (size_t)jt * 4096;
    const ushort* vs = VgL + (size_t)jt * 4096;
    glds16(ks, ldsK0[buf]);       // half 0: d 0..31
    glds16(ks + 32, ldsK1[buf]);  // half 1: d 32..63
    glds16(vs, ldsV0[buf]);       // half 0: kv 0..31
    glds16(vs + 32, ldsV1[buf]);  // half 1: kv 32..63
  };

  const int rkey = (l16 >> 1) & 3;  // read-side swizzle key (row = n*16+l16 or m*16+l16)
  const int b = bh >> 4, h = bh & 15;

  // ---- process one q-tile of 128 rows ----
  auto process = [&](int qt) {
    const int qg0 = qt * 128 + wid * 32;  // wave's min q-row

    // Q fragments direct from global (B-operand of 16x16x32: col=l16, k(d)=h*32+quad*8)
    const ushort* Qg = Qb + ((size_t)bh * 2048 + qg0) * 64;
    bf16x8 qa[2][2];
#pragma unroll
    for (int f = 0; f < 2; ++f)
#pragma unroll
      for (int hh = 0; hh < 2; ++hh)
        qa[f][hh] = *(const bf16x8*)(Qg + (f * 16 + l16) * 64 + hh * 32 + quad * 8);

    f32x4 o[2][4];  // O^T accum: [qfrag][dfrag], row=d(quad*4+r), col=q(l16)
    float rs[2];
#pragma unroll
    for (int f = 0; f < 2; ++f) {
      rs[f] = 0.f;
#pragma unroll
      for (int m = 0; m < 4; ++m) o[f][m] = (f32x4){0.f, 0.f, 0.f, 0.f};
    }

    const int nIt = 2 * qt + 2;  // block-uniform trip count
    stage(0);

    for (int jt = 0; jt < nIt; ++jt) {
      __syncthreads();                   // auto vmcnt(0): tile jt landed
      if (jt + 1 < nIt) stage(jt + 1);   // DMA next tile; lands during this compute phase

      const int kvb = jt * 64;
      if (kvb > qg0 + 31) continue;      // fully-masked for this wave
      const int buf = jt & 1;

      // K fragments: A-operand rows kv=n*16+l16, k(d)=hh*32+quad*8 (swizzled chunk)
      f32x4 s[2][4];
#pragma unroll
      for (int n = 0; n < 4; ++n) {
        const int koff = (n * 16 + l16) * 32 + (quad ^ rkey) * 8;
        bf16x8 kb0 = *(const bf16x8*)&Ks[buf][0][koff];
        bf16x8 kb1 = *(const bf16x8*)&Ks[buf][1][koff];
#pragma unroll
        for (int f = 0; f < 2; ++f) {
          f32x4 z = (f32x4){0.f, 0.f, 0.f, 0.f};
          z = __builtin_amdgcn_mfma_f32_16x16x32_bf16(kb0, qa[f][0], z, 0, 0, 0);
          z = __builtin_amdgcn_mfma_f32_16x16x32_bf16(kb1, qa[f][1], z, 0, 0, 0);
          s[f][n] = z;
        }
      }

      // exp2 + per-lane row-sum + pack P as 16x16x16 B-operand (all in-lane)
      bf16x4 p[2][4];
      if (kvb + 63 <= qg0) {
#pragma unroll
        for (int f = 0; f < 2; ++f)
#pragma unroll
          for (int n = 0; n < 4; ++n) {
            float pe[4];
#pragma unroll
            for (int r = 0; r < 4; ++r) {
              pe[r] = fast_exp2(s[f][n][r]);
              rs[f] += pe[r];
            }
            p[f][n] = (bf16x4){(__bf16)pe[0], (__bf16)pe[1], (__bf16)pe[2], (__bf16)pe[3]};
          }
      } else {
#pragma unroll
        for (int f = 0; f < 2; ++f) {
          const int qg = qg0 + f * 16 + l16;
#pragma unroll
          for (int n = 0; n < 4; ++n) {
            const int kg0 = kvb + n * 16 + quad * 4;
            float pe[4];
#pragma unroll
            for (int r = 0; r < 4; ++r) {
              float e = fast_exp2(s[f][n][r]);
              pe[r] = (kg0 + r > qg) ? 0.f : e;
              rs[f] += pe[r];
            }
            p[f][n] = (bf16x4){(__bf16)pe[0], (__bf16)pe[1], (__bf16)pe[2], (__bf16)pe[3]};
          }
        }
      }

      // O^T += V^T @ P^T  (A-operand: Vs rows d=m*16+l16, k(kv)=n*16+quad*4, swizzled)
#pragma unroll
      for (int m = 0; m < 4; ++m) {
        const int vrow = (m * 16 + l16) * 32;
#pragma unroll
        for (int n = 0; n < 4; ++n) {
          const int clog = (n & 1) * 2 + (quad >> 1);
          const int voff = vrow + (clog ^ rkey) * 8 + (quad & 1) * 4;
          bf16x4 va = *(const bf16x4*)&Vs[buf][n >> 1][voff];
#pragma unroll
          for (int f = 0; f < 2; ++f) o[f][m] = mfma16(va, p[f][n], o[f][m]);
        }
      }
    }

    // epilogue: reduce row sums across quads, normalize, store O (lane holds q=l16)
#pragma unroll
    for (int f = 0; f < 2; ++f) {
      float t = rs[f];
      t += __shfl_xor(t, 16, 64);
      t += __shfl_xor(t, 32, 64);
      const float il = 1.f / t;
      const int q = qg0 + f * 16 + l16;
      ushort* dst = Ob + ((size_t)b * 2048 + q) * 1024 + h * 64;
#pragma unroll
      for (int m = 0; m < 4; ++m) {
        ushort4 w;
        w.x = f2bf(o[f][m][0] * il);
        w.y = f2bf(o[f][m][1] * il);
        w.z = f2bf(o[f][m][2] * il);
        w.w = f2bf(o[f][m][3] * il);
        *(ushort4*)(dst + m * 16 + quad * 4) = w;
      }
    }
  };

  process(15 - pair);  // 34 total iters per block: perfectly uniform
  __syncthreads();     // all waves done with last tile before re-staging buf 0
  process(pair);
}

// ---------------- launch ----------------
extern "C" void kernel_launch(void* const* d_in, const int* in_sizes, int n_in,
                              void* d_out, int out_size, void* d_ws, size_t ws_size,
                              hipStream_t stream) {
  const float* x    = (const float*)d_in[0];  // [4,2048,1024]
  const float* Wqkv = (const float*)d_in[1];  // [1024,3072]
  const float* bqkv = (const float*)d_in[2];  // [3072]
  const float* Wo   = (const float*)d_in[3];  // [1024,1024]
  const float* bo   = (const float*)d_in[4];  // [1024]
  float* out = (float*)d_out;                 // [4,2048,1024] fp32

  char* ws = (char*)d_ws;
  size_t off = 0;
  auto alloc = [&](size_t bytes) {
    void* p = ws + off;
    off += (bytes + 255) & ~(size_t)255;
    return p;
  };
  ushort* xbf    = (ushort*)alloc((size_t)8192 * 1024 * 2);
  ushort* Wqkv_t = (ushort*)alloc((size_t)3072 * 1024 * 2);
  ushort* Wo_t   = (ushort*)alloc((size_t)1024 * 1024 * 2);
  ushort* Qb     = (ushort*)alloc((size_t)64 * 2048 * 64 * 2);
  ushort* Kb     = (ushort*)alloc((size_t)64 * 2048 * 64 * 2);
  ushort* Vb     = (ushort*)alloc((size_t)64 * 2048 * 64 * 2);  // tiled V^T
  ushort* Ab     = (ushort*)alloc((size_t)8192 * 1024 * 2);

  // 1. x -> bf16
  conv_bf16<<<dim3(8192), dim3(256), 0, stream>>>((const float4*)x, (ushort4*)xbf,
                                                  8192 * 1024 / 4);
  // 2. transpose weights -> bf16 [N][K]
  transpose_f32_bf16<<<dim3(96, 32), dim3(32, 8), 0, stream>>>(Wqkv, Wqkv_t, 1024, 3072);
  transpose_f32_bf16<<<dim3(32, 32), dim3(32, 8), 0, stream>>>(Wo, Wo_t, 1024, 1024);
  // 3. QKV projection, scatter to Q/K/Vt layouts (Q pre-scaled by 0.125*log2e)
  gemm_bt<0><<<dim3(24, 64), dim3(256), 0, stream>>>(xbf, Wqkv_t, bqkv, Qb, Kb, Vb, nullptr,
                                                     8192, 3072, 1024);
  // 4. causal flash attention (paired q-tiles: 512 uniform blocks)
  attn_fused<<<dim3(8, 64), dim3(256), 0, stream>>>(Qb, Kb, Vb, Ab);
  // 5. output projection
  gemm_bt<1><<<dim3(8, 64), dim3(256), 0, stream>>>(Ab, Wo_t, bo, nullptr, nullptr, nullptr,
                                                    out, 8192, 1024, 1024);
}

// Round 8
// 273.026 us; speedup vs baseline: 2.0067x; 1.0296x over previous
//
#include <hip/hip_runtime.h>
#include <cstdint>
#include <cstddef>

typedef __bf16 bf16x8 __attribute__((ext_vector_type(8)));
typedef __bf16 bf16x4 __attribute__((ext_vector_type(4)));
typedef short s16x4 __attribute__((ext_vector_type(4)));
typedef float f32x4 __attribute__((ext_vector_type(4)));

__device__ __forceinline__ ushort f2bf(float f) {
  union { float f; uint32_t u; } v; v.f = f;
  uint32_t r = (v.u + 0x7fffu + ((v.u >> 16) & 1u)) >> 16;
  return (ushort)r;
}

__device__ __forceinline__ float fast_exp2(float x) {
#if defined(__HIP_DEVICE_COMPILE__) && __has_builtin(__builtin_amdgcn_exp2f)
  return __builtin_amdgcn_exp2f(x);
#else
  return exp2f(x);
#endif
}

// K=16 bf16 MFMA (C-layout of a 16x16 result feeds directly as B operand).
// __has_builtin guards live inside __HIP_DEVICE_COMPILE__ (host pass has no amdgcn builtins).
__device__ __forceinline__ f32x4 mfma16(bf16x4 a, bf16x4 b, f32x4 c) {
#if defined(__HIP_DEVICE_COMPILE__)
#if __has_builtin(__builtin_amdgcn_mfma_f32_16x16x16_bf16)
  return __builtin_amdgcn_mfma_f32_16x16x16_bf16(a, b, c, 0, 0, 0);
#else
  return __builtin_amdgcn_mfma_f32_16x16x16bf16_1k(
      __builtin_bit_cast(s16x4, a), __builtin_bit_cast(s16x4, b), c, 0, 0, 0);
#endif
#else
  (void)a; (void)b;
  return c;  // host stub, never executed
#endif
}

__device__ __forceinline__ void glds16(const ushort* g, ushort* l) {
  __builtin_amdgcn_global_load_lds((const __attribute__((address_space(1))) void*)g,
                                   (__attribute__((address_space(3))) void*)l, 16, 0, 0);
}

// ---------------- fp32 -> bf16 convert (vectorized) ----------------
__global__ void conv_bf16(const float4* __restrict__ in, ushort4* __restrict__ out, int n4) {
  int i = blockIdx.x * blockDim.x + threadIdx.x;
  if (i < n4) {
    float4 v = in[i];
    ushort4 o;
    o.x = f2bf(v.x); o.y = f2bf(v.y); o.z = f2bf(v.z); o.w = f2bf(v.w);
    out[i] = o;
  }
}

// ---------------- fp32 [R][C] -> bf16 [C][R] transpose ----------------
__global__ void transpose_f32_bf16(const float* __restrict__ in, ushort* __restrict__ out,
                                   int R, int C) {
  __shared__ ushort t[32][33];
  int c0 = blockIdx.x * 32, r0 = blockIdx.y * 32;
  int tx = threadIdx.x, ty = threadIdx.y;  // 32 x 8
#pragma unroll
  for (int i = 0; i < 4; ++i)
    t[ty + i * 8][tx] = f2bf(in[(size_t)(r0 + ty + i * 8) * C + c0 + tx]);
  __syncthreads();
#pragma unroll
  for (int i = 0; i < 4; ++i)
    out[(size_t)(c0 + ty + i * 8) * R + r0 + tx] = t[tx][ty + i * 8];
}

// ---------------- bf16 GEMM: C = A[M][K] @ Bt[N][K]^T + bias ----------------
// MODE 0: epilogue stages each wave's 64x64 C-subtile in private LDS (stride 68:
//   2-way write aliasing, 8B-aligned rows), then writes 128B-coalesced rows:
//   Q[B,H,S,64] (scaled 0.125*log2e), K[B,H,S,64], V^T tiled Vt[bh][s>>6][d][64]
//   (V transposed in LDS). sel is block-uniform; region is wave-private (no barrier).
// MODE 1: fp32 out[row*N+col] direct.
template <int MODE>
__launch_bounds__(256)
__global__ void gemm_bt(const ushort* __restrict__ A, const ushort* __restrict__ Bt,
                        const float* __restrict__ bias,
                        ushort* __restrict__ o0, ushort* __restrict__ o1,
                        ushort* __restrict__ o2, float* __restrict__ of,
                        int M, int N, int K) {
  __shared__ ushort As[128 * 32];
  __shared__ ushort Bs[128 * 32];
  __shared__ ushort Ts[MODE == 0 ? 4 * 64 * 68 : 4];  // per-wave epilogue staging
  const int tid = threadIdx.x;
  const int wid = tid >> 6;
  const int lane = tid & 63;
  const int quad = lane >> 4;
  const int l16 = lane & 15;
  const int m0 = blockIdx.y * 128;
  const int n0 = blockIdx.x * 128;
  const int wm = (wid >> 1) * 64;
  const int wn = (wid & 1) * 64;
  const int srow = lane >> 2;          // 0..15
  const int scol = (lane & 3) << 3;    // 0,8,16,24

  f32x4 acc[4][4];
#pragma unroll
  for (int i = 0; i < 4; ++i)
#pragma unroll
    for (int j = 0; j < 4; ++j) acc[i][j] = (f32x4){0.f, 0.f, 0.f, 0.f};

  const int c0 = wid * 2, c1 = wid * 2 + 1;
  const ushort* gA0 = A + (size_t)(m0 + c0 * 16 + srow) * K + scol;
  const ushort* gA1 = A + (size_t)(m0 + c1 * 16 + srow) * K + scol;
  const ushort* gB0 = Bt + (size_t)(n0 + c0 * 16 + srow) * K + scol;
  const ushort* gB1 = Bt + (size_t)(n0 + c1 * 16 + srow) * K + scol;
  ushort* lA0 = As + c0 * 512 + lane * 8;
  ushort* lA1 = As + c1 * 512 + lane * 8;
  ushort* lB0 = Bs + c0 * 512 + lane * 8;
  ushort* lB1 = Bs + c1 * 512 + lane * 8;

  for (int k0 = 0; k0 < K; k0 += 32) {
    __syncthreads();
    glds16(gA0 + k0, lA0);
    glds16(gA1 + k0, lA1);
    glds16(gB0 + k0, lB0);
    glds16(gB1 + k0, lB1);
    __syncthreads();
    bf16x8 af[4], bfr[4];
#pragma unroll
    for (int i = 0; i < 4; ++i)
      af[i] = *(const bf16x8*)(As + (wm + i * 16 + l16) * 32 + quad * 8);
#pragma unroll
    for (int j = 0; j < 4; ++j)
      bfr[j] = *(const bf16x8*)(Bs + (wn + j * 16 + l16) * 32 + quad * 8);
#pragma unroll
    for (int i = 0; i < 4; ++i)
#pragma unroll
      for (int j = 0; j < 4; ++j)
        acc[i][j] = __builtin_amdgcn_mfma_f32_16x16x32_bf16(af[i], bfr[j], acc[i][j], 0, 0, 0);
  }

  if (MODE == 1) {
#pragma unroll
    for (int i = 0; i < 4; ++i)
#pragma unroll
      for (int j = 0; j < 4; ++j) {
        const int col = n0 + wn + j * 16 + l16;
        const float bv = bias[col];
#pragma unroll
        for (int r = 0; r < 4; ++r) {
          const int row = m0 + wm + i * 16 + quad * 4 + r;
          of[(size_t)row * N + col] = acc[i][j][r] + bv;
        }
      }
  } else {
    ushort* T = &Ts[wid * (64 * 68)];
    const int col0 = n0 + wn;            // block+wave uniform
    const int sel = col0 >> 10;          // 0=Q 1=K 2=V
    const int hh = (col0 & 1023) >> 6;
    const int row0 = m0 + wm;
    const int bb = row0 >> 11;
    const int s0 = row0 & 2047;
    const size_t bh = (size_t)(bb * 16 + hh);
    // stage fragments into LDS: [s][d] for Q/K, transposed [d][s] for V
#pragma unroll
    for (int j = 0; j < 4; ++j) {
      const float bv = bias[col0 + j * 16 + l16];
      const int dl = j * 16 + l16;
#pragma unroll
      for (int i = 0; i < 4; ++i) {
#pragma unroll
        for (int r = 0; r < 4; ++r) {
          const int sl = i * 16 + quad * 4 + r;
          float v = acc[i][j][r] + bv;
          if (sel == 0) v *= 0.18033688011112042f;  // (1/8)*log2(e): exp -> exp2
          const ushort u = f2bf(v);
          if (sel == 2) T[dl * 68 + sl] = u;
          else          T[sl * 68 + dl] = u;
        }
      }
    }
    asm volatile("s_waitcnt lgkmcnt(0)" ::: "memory");  // wave-local W->R ordering
    // each lane writes one full 64-elem row: 128B coalesced
    ushort* dst;
    if (sel == 2) dst = o2 + ((bh * 32 + (s0 >> 6)) << 12) + lane * 64;
    else          dst = (sel == 0 ? o0 : o1) + (bh * 2048 + s0 + lane) * 64;
    const ushort* Trow = &T[lane * 68];
#pragma unroll
    for (int k = 0; k < 16; ++k)
      *(ushort4*)(dst + k * 4) = *(const ushort4*)(Trow + k * 4);
  }
}

// ---------------- flash attention (causal) ----------------
// Block p of 8 processes q-tiles {p, 15-p} (128 rows each) for its (b,h):
// uniform 34 KV-iters/block -> 512 blocks = 2/CU, no tail.
// Single-barrier dbuf global_load_lds staging; source-side XOR swizzle (DMA dest is
// forced to base+lane*16B) -> b128/b64 LDS reads 2-way aliased (free).
// P stays in registers: S'=K@Q^T (16x16x32) C-layout feeds PV (16x16x16) directly.
__launch_bounds__(256)
__global__ void attn_fused(const ushort* __restrict__ Qb, const ushort* __restrict__ Kb,
                           const ushort* __restrict__ Vt, ushort* __restrict__ Ob) {
  const int bh = blockIdx.y;       // b*16 + h
  const int pair = blockIdx.x;     // 0..7
  const int tid = threadIdx.x;
  const int wid = tid >> 6;
  const int lane = tid & 63;
  const int quad = lane >> 4;
  const int l16 = lane & 15;

  __shared__ ushort Ks[2][2][64 * 32];  // [buf][half(d)][row=kv][32 d-elems] (swizzled)
  __shared__ ushort Vs[2][2][64 * 32];  // [buf][half(kv)][row=d][32 kv-elems] (swizzled)

  // staging: wave w covers rows w*16..w*16+15; lane -> (row = w*16 + lane>>2, j_phys = lane&3)
  const int lr = lane >> 2;
  const int jphys = lane & 3;
  const int skey = (lr >> 1) & 3;           // swizzle key for this lane's staged row
  const int jlog = jphys ^ skey;            // logical chunk this lane fetches
  const int srow = wid * 16 + lr;           // row within 64-row tile
  const ushort* KgL = Kb + (size_t)bh * 2048 * 64 + (size_t)srow * 64 + jlog * 8;
  const ushort* VgL = Vt + (size_t)bh * 32 * 4096 + (size_t)srow * 64 + jlog * 8;
  ushort* ldsK0[2], *ldsK1[2], *ldsV0[2], *ldsV1[2];
#pragma unroll
  for (int buf = 0; buf < 2; ++buf) {
    ldsK0[buf] = &Ks[buf][0][wid * 16 * 32] + lane * 8;
    ldsK1[buf] = &Ks[buf][1][wid * 16 * 32] + lane * 8;
    ldsV0[buf] = &Vs[buf][0][wid * 16 * 32] + lane * 8;
    ldsV1[buf] = &Vs[buf][1][wid * 16 * 32] + lane * 8;
  }
  auto stage = [&](int jt) {
    const int buf = jt & 1;
    const ushort* ks = KgL + (size_t)jt * 4096;
    const ushort* vs = VgL + (size_t)jt * 4096;
    glds16(ks, ldsK0[buf]);       // half 0: d 0..31
    glds16(ks + 32, ldsK1[buf]);  // half 1: d 32..63
    glds16(vs, ldsV0[buf]);       // half 0: kv 0..31
    glds16(vs + 32, ldsV1[buf]);  // half 1: kv 32..63
  };

  const int rkey = (l16 >> 1) & 3;  // read-side swizzle key (row = n*16+l16 or m*16+l16)
  const int b = bh >> 4, h = bh & 15;

  // ---- process one q-tile of 128 rows ----
  auto process = [&](int qt) {
    const int qg0 = qt * 128 + wid * 32;  // wave's min q-row

    // Q fragments direct from global (B-operand of 16x16x32: col=l16, k(d)=h*32+quad*8)
    const ushort* Qg = Qb + ((size_t)bh * 2048 + qg0) * 64;
    bf16x8 qa[2][2];
#pragma unroll
    for (int f = 0; f < 2; ++f)
#pragma unroll
      for (int hh = 0; hh < 2; ++hh)
        qa[f][hh] = *(const bf16x8*)(Qg + (f * 16 + l16) * 64 + hh * 32 + quad * 8);

    f32x4 o[2][4];  // O^T accum: [qfrag][dfrag], row=d(quad*4+r), col=q(l16)
    float rs[2];
#pragma unroll
    for (int f = 0; f < 2; ++f) {
      rs[f] = 0.f;
#pragma unroll
      for (int m = 0; m < 4; ++m) o[f][m] = (f32x4){0.f, 0.f, 0.f, 0.f};
    }

    const int nIt = 2 * qt + 2;  // block-uniform trip count
    stage(0);

    for (int jt = 0; jt < nIt; ++jt) {
      __syncthreads();                   // auto vmcnt(0): tile jt landed
      if (jt + 1 < nIt) stage(jt + 1);   // DMA next tile; lands during this compute phase

      const int kvb = jt * 64;
      if (kvb > qg0 + 31) continue;      // fully-masked for this wave
      const int buf = jt & 1;

      // K fragments: A-operand rows kv=n*16+l16, k(d)=hh*32+quad*8 (swizzled chunk)
      f32x4 s[2][4];
#pragma unroll
      for (int n = 0; n < 4; ++n) {
        const int koff = (n * 16 + l16) * 32 + (quad ^ rkey) * 8;
        bf16x8 kb0 = *(const bf16x8*)&Ks[buf][0][koff];
        bf16x8 kb1 = *(const bf16x8*)&Ks[buf][1][koff];
#pragma unroll
        for (int f = 0; f < 2; ++f) {
          f32x4 z = (f32x4){0.f, 0.f, 0.f, 0.f};
          z = __builtin_amdgcn_mfma_f32_16x16x32_bf16(kb0, qa[f][0], z, 0, 0, 0);
          z = __builtin_amdgcn_mfma_f32_16x16x32_bf16(kb1, qa[f][1], z, 0, 0, 0);
          s[f][n] = z;
        }
      }

      // exp2 + per-lane row-sum + pack P as 16x16x16 B-operand (all in-lane)
      bf16x4 p[2][4];
      if (kvb + 63 <= qg0) {
#pragma unroll
        for (int f = 0; f < 2; ++f)
#pragma unroll
          for (int n = 0; n < 4; ++n) {
            float pe[4];
#pragma unroll
            for (int r = 0; r < 4; ++r) {
              pe[r] = fast_exp2(s[f][n][r]);
              rs[f] += pe[r];
            }
            p[f][n] = (bf16x4){(__bf16)pe[0], (__bf16)pe[1], (__bf16)pe[2], (__bf16)pe[3]};
          }
      } else {
#pragma unroll
        for (int f = 0; f < 2; ++f) {
          const int qg = qg0 + f * 16 + l16;
#pragma unroll
          for (int n = 0; n < 4; ++n) {
            const int kg0 = kvb + n * 16 + quad * 4;
            float pe[4];
#pragma unroll
            for (int r = 0; r < 4; ++r) {
              float e = fast_exp2(s[f][n][r]);
              pe[r] = (kg0 + r > qg) ? 0.f : e;
              rs[f] += pe[r];
            }
            p[f][n] = (bf16x4){(__bf16)pe[0], (__bf16)pe[1], (__bf16)pe[2], (__bf16)pe[3]};
          }
        }
      }

      // O^T += V^T @ P^T  (A-operand: Vs rows d=m*16+l16, k(kv)=n*16+quad*4, swizzled)
#pragma unroll
      for (int m = 0; m < 4; ++m) {
        const int vrow = (m * 16 + l16) * 32;
#pragma unroll
        for (int n = 0; n < 4; ++n) {
          const int clog = (n & 1) * 2 + (quad >> 1);
          const int voff = vrow + (clog ^ rkey) * 8 + (quad & 1) * 4;
          bf16x4 va = *(const bf16x4*)&Vs[buf][n >> 1][voff];
#pragma unroll
          for (int f = 0; f < 2; ++f) o[f][m] = mfma16(va, p[f][n], o[f][m]);
        }
      }
    }

    // epilogue: reduce row sums across quads, normalize, store O (lane holds q=l16)
#pragma unroll
    for (int f = 0; f < 2; ++f) {
      float t = rs[f];
      t += __shfl_xor(t, 16, 64);
      t += __shfl_xor(t, 32, 64);
      const float il = 1.f / t;
      const int q = qg0 + f * 16 + l16;
      ushort* dst = Ob + ((size_t)b * 2048 + q) * 1024 + h * 64;
#pragma unroll
      for (int m = 0; m < 4; ++m) {
        ushort4 w;
        w.x = f2bf(o[f][m][0] * il);
        w.y = f2bf(o[f][m][1] * il);
        w.z = f2bf(o[f][m][2] * il);
        w.w = f2bf(o[f][m][3] * il);
        *(ushort4*)(dst + m * 16 + quad * 4) = w;
      }
    }
  };

  process(15 - pair);  // 34 total iters per block: perfectly uniform
  __syncthreads();     // all waves done with last tile before re-staging buf 0
  process(pair);
}

// ---------------- launch ----------------
extern "C" void kernel_launch(void* const* d_in, const int* in_sizes, int n_in,
                              void* d_out, int out_size, void* d_ws, size_t ws_size,
                              hipStream_t stream) {
  const float* x    = (const float*)d_in[0];  // [4,2048,1024]
  const float* Wqkv = (const float*)d_in[1];  // [1024,3072]
  const float* bqkv = (const float*)d_in[2];  // [3072]
  const float* Wo   = (const float*)d_in[3];  // [1024,1024]
  const float* bo   = (const float*)d_in[4];  // [1024]
  float* out = (float*)d_out;                 // [4,2048,1024] fp32

  char* ws = (char*)d_ws;
  size_t off = 0;
  auto alloc = [&](size_t bytes) {
    void* p = ws + off;
    off += (bytes + 255) & ~(size_t)255;
    return p;
  };
  ushort* xbf    = (ushort*)alloc((size_t)8192 * 1024 * 2);
  ushort* Wqkv_t = (ushort*)alloc((size_t)3072 * 1024 * 2);
  ushort* Wo_t   = (ushort*)alloc((size_t)1024 * 1024 * 2);
  ushort* Qb     = (ushort*)alloc((size_t)64 * 2048 * 64 * 2);
  ushort* Kb     = (ushort*)alloc((size_t)64 * 2048 * 64 * 2);
  ushort* Vb     = (ushort*)alloc((size_t)64 * 2048 * 64 * 2);  // tiled V^T
  ushort* Ab     = (ushort*)alloc((size_t)8192 * 1024 * 2);

  // 1. x -> bf16
  conv_bf16<<<dim3(8192), dim3(256), 0, stream>>>((const float4*)x, (ushort4*)xbf,
                                                  8192 * 1024 / 4);
  // 2. transpose weights -> bf16 [N][K]
  transpose_f32_bf16<<<dim3(96, 32), dim3(32, 8), 0, stream>>>(Wqkv, Wqkv_t, 1024, 3072);
  transpose_f32_bf16<<<dim3(32, 32), dim3(32, 8), 0, stream>>>(Wo, Wo_t, 1024, 1024);
  // 3. QKV projection, scatter to Q/K/Vt layouts (Q pre-scaled by 0.125*log2e)
  gemm_bt<0><<<dim3(24, 64), dim3(256), 0, stream>>>(xbf, Wqkv_t, bqkv, Qb, Kb, Vb, nullptr,
                                                     8192, 3072, 1024);
  // 4. causal flash attention (paired q-tiles: 512 uniform blocks)
  attn_fused<<<dim3(8, 64), dim3(256), 0, stream>>>(Qb, Kb, Vb, Ab);
  // 5. output projection
  gemm_bt<1><<<dim3(8, 64), dim3(256), 0, stream>>>(Ab, Wo_t, bo, nullptr, nullptr, nullptr,
                                                    out, 8192, 1024, 1024);
}